// Round 8
// baseline (2405.877 us; speedup 1.0000x reference)
//
#include <hip/hip_runtime.h>
#include <hip/hip_bf16.h>

#define NROW 16384
#define NFEATC 512
#define NH1 256
#define NH2 128
#define NCLS 8

typedef __attribute__((ext_vector_type(8))) short short8;
typedef __attribute__((ext_vector_type(4))) float f32x4;

__device__ __forceinline__ ushort f2bf(float f) {
  union { float f; unsigned u; } v; v.f = f;
  unsigned r = v.u + 0x7FFFu + ((v.u >> 16) & 1u);
  return (ushort)(r >> 16);
}
__device__ __forceinline__ float bf2f(ushort h) {
  union { unsigned u; float f; } v; v.u = ((unsigned)h) << 16; return v.f;
}
__device__ __forceinline__ short8 cvt8(const float4& a, const float4& b) {
  short8 v;
  v[0] = (short)f2bf(a.x); v[1] = (short)f2bf(a.y);
  v[2] = (short)f2bf(a.z); v[3] = (short)f2bf(a.w);
  v[4] = (short)f2bf(b.x); v[5] = (short)f2bf(b.y);
  v[6] = (short)f2bf(b.z); v[7] = (short)f2bf(b.w);
  return v;
}

// in [K][N] fp32 -> out [N][K] bf16
__global__ __launch_bounds__(256) void transpose_conv(
    const float* __restrict__ in, ushort* __restrict__ out, int K, int N) {
  int idx = blockIdx.x * 256 + threadIdx.x;
  if (idx < K * N) {
    int k = idx / N, n = idx % N;
    out[(size_t)n * K + k] = f2bf(in[idx]);
  }
}

// ---------------------------------------------------------------------------
// gemm_pipe: reg-staged LDS path for the small-K GEMMs (x@W1, h1@W2). Proven.
template<int BM, int BN, int WM, int WN, int KSPLIT, bool AFP32, int OUTM, int MINW>
__global__ __launch_bounds__(256, MINW) void gemm_pipe(
    const void* __restrict__ Ap, const ushort* __restrict__ BT,
    void* __restrict__ Outp, const float* __restrict__ bias,
    const int nm, const int nn, const int M, const int N, const int K)
{
  constexpr int BK = 64, LDSK = BK + 8;
  constexpr int MR = WM / 16, NR = WN / 16;
  constexpr int nWc = BN / WN;
  static_assert((BM / WM) * (BN / WN) == 4, "4 waves");
  constexpr int AELEM = BM * BK / 256, ATPR = BK / AELEM;
  constexpr int BELEM = BN * BK / 256, BTPR = BK / BELEM;
  constexpr int A4s = AFP32 ? AELEM / 4 : 1;
  constexpr int A8s = AFP32 ? 1 : AELEM / 8;
  constexpr int B8s = (BELEM >= 8) ? BELEM / 8 : 1;

  __shared__ ushort As[2][BM * LDSK];
  __shared__ ushort Bs[2][BN * LDSK];

  const int t = threadIdx.x, l = t & 63, wid = t >> 6;
  const int wr0 = (wid / nWc) * WM, wc0 = (wid % nWc) * WN;

  const int cpx = gridDim.x >> 3;
  const int flat = (blockIdx.x & 7) * cpx + (blockIdx.x >> 3);
  const int n_blk = flat % nn;
  const int m_blk = (flat / nn) % nm;
  const int ksl = flat / (nn * nm);
  const int bm0 = m_blk * BM, bn0 = n_blk * BN;
  const int kper = K / KSPLIT, kbase = ksl * kper;
  const int NT = kper / BK;

  const int ar = t / ATPR, ak = (t % ATPR) * AELEM;
  const int br = t / BTPR, bk = (t % BTPR) * BELEM;

  const float*  Af = (const float*)Ap + (size_t)(bm0 + ar) * K + kbase + ak;
  const ushort* Ab = (const ushort*)Ap + (size_t)(bm0 + ar) * K + kbase + ak;
  const ushort* Bp = BT + (size_t)(bn0 + br) * K + kbase + bk;

  f32x4 acc[MR][NR] = {};

  float4 aF[A4s];
  short8 aB[A8s];
  short8 bV[B8s];
  ushort4 b4;

  auto loadRegs = [&](int it) {
    const int ko = it * BK;
    if constexpr (AFP32) {
      #pragma unroll
      for (int c = 0; c < A4s; c++) aF[c] = *(const float4*)(Af + ko + 4 * c);
    } else {
      #pragma unroll
      for (int c = 0; c < A8s; c++) aB[c] = *(const short8*)(Ab + ko + 8 * c);
    }
    if constexpr (BELEM >= 8) {
      #pragma unroll
      for (int c = 0; c < B8s; c++) bV[c] = *(const short8*)(Bp + ko + 8 * c);
    } else {
      b4 = *(const ushort4*)(Bp + ko);
    }
  };

  auto writeLds = [&](int buf) {
    if constexpr (AFP32) {
      #pragma unroll
      for (int c = 0; c < A4s; c++) {
        ushort4 v;
        v.x = f2bf(aF[c].x); v.y = f2bf(aF[c].y);
        v.z = f2bf(aF[c].z); v.w = f2bf(aF[c].w);
        *(ushort4*)&As[buf][ar * LDSK + ak + 4 * c] = v;
      }
    } else {
      #pragma unroll
      for (int c = 0; c < A8s; c++)
        *(short8*)&As[buf][ar * LDSK + ak + 8 * c] = aB[c];
    }
    if constexpr (BELEM >= 8) {
      #pragma unroll
      for (int c = 0; c < B8s; c++)
        *(short8*)&Bs[buf][br * LDSK + bk + 8 * c] = bV[c];
    } else {
      *(ushort4*)&Bs[buf][br * LDSK + bk] = b4;
    }
  };

  auto compute = [&](int buf) {
    const int rr = l & 15;
    #pragma unroll
    for (int kk = 0; kk < 2; kk++) {
      const int kb = kk * 32 + (l >> 4) * 8;
      short8 af[MR], bfv[NR];
      #pragma unroll
      for (int m = 0; m < MR; m++)
        af[m] = *(short8*)&As[buf][(wr0 + m * 16 + rr) * LDSK + kb];
      #pragma unroll
      for (int n = 0; n < NR; n++)
        bfv[n] = *(short8*)&Bs[buf][(wc0 + n * 16 + rr) * LDSK + kb];
      #pragma unroll
      for (int m = 0; m < MR; m++)
        #pragma unroll
        for (int n = 0; n < NR; n++)
          acc[m][n] = __builtin_amdgcn_mfma_f32_16x16x32_bf16(af[m], bfv[n], acc[m][n], 0, 0, 0);
    }
  };

  loadRegs(0);
  writeLds(0);
  __syncthreads();
  for (int it = 0; it < NT; it++) {
    const int cur = it & 1;
    if (it + 1 < NT) loadRegs(it + 1);
    compute(cur);
    if (it + 1 < NT) writeLds(cur ^ 1);
    __syncthreads();
  }

  #pragma unroll
  for (int m = 0; m < MR; m++) {
    const int row = bm0 + wr0 + m * 16 + (l >> 4) * 4;
    #pragma unroll
    for (int n = 0; n < NR; n++) {
      const int col = bn0 + wc0 + n * 16 + (l & 15);
      if constexpr (OUTM == 1) {
        ushort4 v;
        v.x = f2bf(acc[m][n][0]); v.y = f2bf(acc[m][n][1]);
        v.z = f2bf(acc[m][n][2]); v.w = f2bf(acc[m][n][3]);
        *(ushort4*)((ushort*)Outp + (size_t)col * M + row) = v;
      } else {
        const float bv = bias[col];
        ushort* o = (ushort*)Outp;
        #pragma unroll
        for (int r = 0; r < 4; r++)
          o[(size_t)(row + r) * N + col] = f2bf(fmaxf(acc[m][n][r] + bv, 0.0f));
      }
    }
  }
}

// ---------------------------------------------------------------------------
// h1_direct: h1[M][256] = relu(adj @ s1 + b1), fused adjBF writeout.
// NO LDS, NO barriers. 4 waves = 4Mx1N; block = 64 rows x 64 cols; nn=4
// (n-fastest + XCD swizzle -> 4 col-blocks co-resident share the adj panel
// via L2). A-fragments loaded straight from global in MFMA lane layout
// (row = l&15, k = (l>>4)*8 : 128B contiguous per row -> full lines).
// Depth-2 named register pipeline; compiler emits counted waitcnts.
__global__ __launch_bounds__(256, 4) void h1_direct(
    const float* __restrict__ adj, const ushort* __restrict__ s1T,
    const float* __restrict__ b1, ushort* __restrict__ h1,
    ushort* __restrict__ adjBF)
{
  constexpr int NT = NROW / 32;   // 512
  const int t = threadIdx.x, l = t & 63, w = t >> 6;
  const int rr = l & 15, hi = l >> 4;

  const int cpx = gridDim.x >> 3;
  const int flat = (blockIdx.x & 7) * cpx + (blockIdx.x >> 3);
  const int n_blk = flat & 3;
  const int m_blk = flat >> 2;          // 0..255
  const int bm0 = m_blk * 64, bn0 = n_blk * 64;
  const int row = bm0 + w * 16 + rr;
  const bool wb = (n_blk == 0);

  const float* Ap = adj + (size_t)row * NROW + hi * 8;
  ushort* Wp = adjBF + (size_t)row * NROW + hi * 8;
  const ushort* Bp0 = s1T + (size_t)(bn0 + 0 * 16 + rr) * NROW + hi * 8;
  const ushort* Bp1 = s1T + (size_t)(bn0 + 1 * 16 + rr) * NROW + hi * 8;
  const ushort* Bp2 = s1T + (size_t)(bn0 + 2 * 16 + rr) * NROW + hi * 8;
  const ushort* Bp3 = s1T + (size_t)(bn0 + 3 * 16 + rr) * NROW + hi * 8;

  f32x4 acc0 = {}, acc1 = {}, acc2 = {}, acc3 = {};
  float4 aX0, aX1, aY0, aY1;
  short8 bX0, bX1, bX2, bX3, bY0, bY1, bY2, bY3;

  // prologue: iter 0 -> X
  aX0 = *(const float4*)(Ap);     aX1 = *(const float4*)(Ap + 4);
  bX0 = *(const short8*)(Bp0);    bX1 = *(const short8*)(Bp1);
  bX2 = *(const short8*)(Bp2);    bX3 = *(const short8*)(Bp3);

  for (int it = 0; it < NT; it += 2) {
    // load it+1 -> Y
    if (it + 1 < NT) {
      const int ko = (it + 1) * 32;
      aY0 = *(const float4*)(Ap + ko); aY1 = *(const float4*)(Ap + ko + 4);
      bY0 = *(const short8*)(Bp0 + ko); bY1 = *(const short8*)(Bp1 + ko);
      bY2 = *(const short8*)(Bp2 + ko); bY3 = *(const short8*)(Bp3 + ko);
    }
    // process X (iter it)
    {
      short8 v = cvt8(aX0, aX1);
      if (wb) *(short8*)(Wp + it * 32) = v;
      acc0 = __builtin_amdgcn_mfma_f32_16x16x32_bf16(v, bX0, acc0, 0, 0, 0);
      acc1 = __builtin_amdgcn_mfma_f32_16x16x32_bf16(v, bX1, acc1, 0, 0, 0);
      acc2 = __builtin_amdgcn_mfma_f32_16x16x32_bf16(v, bX2, acc2, 0, 0, 0);
      acc3 = __builtin_amdgcn_mfma_f32_16x16x32_bf16(v, bX3, acc3, 0, 0, 0);
    }
    // load it+2 -> X
    if (it + 2 < NT) {
      const int ko = (it + 2) * 32;
      aX0 = *(const float4*)(Ap + ko); aX1 = *(const float4*)(Ap + ko + 4);
      bX0 = *(const short8*)(Bp0 + ko); bX1 = *(const short8*)(Bp1 + ko);
      bX2 = *(const short8*)(Bp2 + ko); bX3 = *(const short8*)(Bp3 + ko);
    }
    // process Y (iter it+1)
    if (it + 1 < NT) {
      short8 v = cvt8(aY0, aY1);
      if (wb) *(short8*)(Wp + (it + 1) * 32) = v;
      acc0 = __builtin_amdgcn_mfma_f32_16x16x32_bf16(v, bY0, acc0, 0, 0, 0);
      acc1 = __builtin_amdgcn_mfma_f32_16x16x32_bf16(v, bY1, acc1, 0, 0, 0);
      acc2 = __builtin_amdgcn_mfma_f32_16x16x32_bf16(v, bY2, acc2, 0, 0, 0);
      acc3 = __builtin_amdgcn_mfma_f32_16x16x32_bf16(v, bY3, acc3, 0, 0, 0);
    }
  }

  // epilogue: relu(acc + b1[col]) -> h1 bf16 [M][256]
  const int orow = bm0 + w * 16 + hi * 4;
  f32x4 av[4] = {acc0, acc1, acc2, acc3};
  #pragma unroll
  for (int n = 0; n < 4; n++) {
    const int col = bn0 + n * 16 + rr;
    const float bv = b1[col];
    #pragma unroll
    for (int r = 0; r < 4; r++)
      h1[(size_t)(orow + r) * NH1 + col] = f2bf(fmaxf(av[n][r] + bv, 0.0f));
  }
}

// ---------------------------------------------------------------------------
// h2_direct: part[ksl][M][128] = adjBF @ s2 (k-slice). NO LDS, NO barriers.
// 4 waves = 4Mx1N; block = 64 rows x 128 cols (nn=1); split-K=4 -> grid 1024.
__global__ __launch_bounds__(256, 3) void h2_direct(
    const ushort* __restrict__ adjBF, const ushort* __restrict__ s2T,
    float* __restrict__ part)
{
  constexpr int NT = 4096 / 32;   // 128 per ksl
  const int t = threadIdx.x, l = t & 63, w = t >> 6;
  const int rr = l & 15, hi = l >> 4;

  const int cpx = gridDim.x >> 3;
  const int flat = (blockIdx.x & 7) * cpx + (blockIdx.x >> 3);
  const int m_blk = flat & 255;
  const int ksl = flat >> 8;            // 0..3
  const int bm0 = m_blk * 64;
  const int kbase = ksl * 4096;
  const int row = bm0 + w * 16 + rr;

  const ushort* Ap = adjBF + (size_t)row * NROW + kbase + hi * 8;
  const ushort* Bb = s2T + (size_t)rr * NROW + kbase + hi * 8;
  const size_t cstr = (size_t)16 * NROW;

  f32x4 acc[8] = {};
  short8 aX, aY;
  short8 bX[8], bY[8];

  aX = *(const short8*)(Ap);
  #pragma unroll
  for (int n = 0; n < 8; n++) bX[n] = *(const short8*)(Bb + n * cstr);

  for (int it = 0; it < NT; it += 2) {
    if (it + 1 < NT) {
      const int ko = (it + 1) * 32;
      aY = *(const short8*)(Ap + ko);
      #pragma unroll
      for (int n = 0; n < 8; n++) bY[n] = *(const short8*)(Bb + n * cstr + ko);
    }
    #pragma unroll
    for (int n = 0; n < 8; n++)
      acc[n] = __builtin_amdgcn_mfma_f32_16x16x32_bf16(aX, bX[n], acc[n], 0, 0, 0);
    if (it + 2 < NT) {
      const int ko = (it + 2) * 32;
      aX = *(const short8*)(Ap + ko);
      #pragma unroll
      for (int n = 0; n < 8; n++) bX[n] = *(const short8*)(Bb + n * cstr + ko);
    }
    if (it + 1 < NT) {
      #pragma unroll
      for (int n = 0; n < 8; n++)
        acc[n] = __builtin_amdgcn_mfma_f32_16x16x32_bf16(aY, bY[n], acc[n], 0, 0, 0);
    }
  }

  float* o = part + (size_t)ksl * NROW * NH2;
  const int orow = bm0 + w * 16 + hi * 4;
  #pragma unroll
  for (int n = 0; n < 8; n++) {
    const int col = n * 16 + rr;
    #pragma unroll
    for (int r = 0; r < 4; r++)
      o[(size_t)(orow + r) * NH2 + col] = acc[n][r];
  }
}

// ---------------------------------------------------------------------------
// gemm_fin: part[8][16384][16] = adjBF @ s3 (s3T padded to 16 cols).
// Pure register streaming: no LDS, no barriers; B is L3-resident. (Proven R7.)
__global__ __launch_bounds__(256, 4) void gemm_fin(
    const ushort* __restrict__ adjBF, const ushort* __restrict__ s3T,
    float* __restrict__ part)
{
  const int t = threadIdx.x, l = t & 63, wid = t >> 6;   // 4 waves
  const int rr = l & 15, hi = l >> 4;

  const int cpx = gridDim.x >> 3;
  const int flat = (blockIdx.x & 7) * cpx + (blockIdx.x >> 3);
  const int m_blk = flat & 127;
  const int ksl = flat >> 7;                   // 0..7
  const int bm0 = m_blk * 128;
  const int kbase = ksl * 2048;

  const ushort* A0 = adjBF + (size_t)(bm0 + wid * 32 + rr) * NROW + kbase + hi * 8;
  const ushort* A1 = A0 + (size_t)16 * NROW;
  const ushort* Bp = s3T + (size_t)rr * NROW + kbase + hi * 8;

  f32x4 acc0 = {}, acc1 = {};
  #pragma unroll 8
  for (int k = 0; k < 64; k++) {
    short8 a0 = *(const short8*)(A0 + k * 32);
    short8 a1 = *(const short8*)(A1 + k * 32);
    short8 b  = *(const short8*)(Bp + k * 32);
    acc0 = __builtin_amdgcn_mfma_f32_16x16x32_bf16(a0, b, acc0, 0, 0, 0);
    acc1 = __builtin_amdgcn_mfma_f32_16x16x32_bf16(a1, b, acc1, 0, 0, 0);
  }

  float* o = part + (size_t)ksl * NROW * 16;
  #pragma unroll
  for (int r = 0; r < 4; r++) {
    o[(size_t)(bm0 + wid * 32 + hi * 4 + r) * 16 + rr] = acc0[r];
    o[(size_t)(bm0 + wid * 32 + 16 + hi * 4 + r) * 16 + rr] = acc1[r];
  }
}

// out[M][N] bf16 = relu(sum_k part[k][M][N] + bias[col]); vectorized by 4
__global__ __launch_bounds__(256) void reduce_relu(
    const float* __restrict__ part, const float* __restrict__ bias,
    ushort* __restrict__ out, const int MN, const int N, const int KS) {
  const int i4 = (blockIdx.x * 256 + threadIdx.x) * 4;
  if (i4 >= MN) return;
  float4 s = *(const float4*)(part + i4);
  for (int k = 1; k < KS; k++) {
    float4 p = *(const float4*)(part + (size_t)k * MN + i4);
    s.x += p.x; s.y += p.y; s.z += p.z; s.w += p.w;
  }
  const int col = i4 % N;
  float4 b = *(const float4*)(bias + col);
  ushort4 v;
  v.x = f2bf(fmaxf(s.x + b.x, 0.0f));
  v.y = f2bf(fmaxf(s.y + b.y, 0.0f));
  v.z = f2bf(fmaxf(s.z + b.z, 0.0f));
  v.w = f2bf(fmaxf(s.w + b.w, 0.0f));
  *(ushort4*)(out + i4) = v;
}

// s3T[16][NROW] bf16 = (h2 @ W3)^T, rows 8..15 zero-padded. 64-thr blocks.
__global__ __launch_bounds__(64) void mm_small(
    const ushort* __restrict__ h2, const float* __restrict__ W3,
    ushort* __restrict__ s3T) {
  __shared__ float w[NH2 * NCLS];
  for (int i = threadIdx.x; i < NH2 * NCLS; i += 64) w[i] = W3[i];
  __syncthreads();
  const int m = blockIdx.x * 64 + threadIdx.x;
  float acc[8] = {};
  const ushort* row = h2 + (size_t)m * NH2;
  #pragma unroll
  for (int c = 0; c < NH2 / 8; c++) {
    short8 v = *(const short8*)(row + c * 8);
    #pragma unroll
    for (int j = 0; j < 8; j++) {
      float h = bf2f((ushort)v[j]);
      const int k = c * 8 + j;
      #pragma unroll
      for (int n = 0; n < 8; n++) acc[n] += h * w[k * 8 + n];
    }
  }
  #pragma unroll
  for (int n = 0; n < 8; n++) s3T[(size_t)n * NROW + m] = f2bf(acc[n]);
  #pragma unroll
  for (int n = 8; n < 16; n++) s3T[(size_t)n * NROW + m] = 0;
}

// out[NROW][8] = log_softmax(sum_ksl part + b3), KS=8
__global__ __launch_bounds__(256) void final_reduce(
    const float* __restrict__ part, const float* __restrict__ b3,
    float* __restrict__ out) {
  const int m = blockIdx.x * 256 + threadIdx.x;
  float4 s0 = make_float4(0, 0, 0, 0), s1 = make_float4(0, 0, 0, 0);
  #pragma unroll
  for (int k = 0; k < 8; k++) {
    const float4* p = (const float4*)(part + ((size_t)k * NROW + m) * 16);
    float4 a = p[0], b = p[1];
    s0.x += a.x; s0.y += a.y; s0.z += a.z; s0.w += a.w;
    s1.x += b.x; s1.y += b.y; s1.z += b.z; s1.w += b.w;
  }
  float v[8];
  v[0] = s0.x + b3[0]; v[1] = s0.y + b3[1]; v[2] = s0.z + b3[2]; v[3] = s0.w + b3[3];
  v[4] = s1.x + b3[4]; v[5] = s1.y + b3[5]; v[6] = s1.z + b3[6]; v[7] = s1.w + b3[7];
  float mx = v[0];
  #pragma unroll
  for (int n = 1; n < 8; n++) mx = fmaxf(mx, v[n]);
  float s = 0.0f;
  #pragma unroll
  for (int n = 0; n < 8; n++) s += expf(v[n] - mx);
  const float lse = logf(s) + mx;
  float4* o = (float4*)(out + (size_t)m * 8);
  o[0] = make_float4(v[0] - lse, v[1] - lse, v[2] - lse, v[3] - lse);
  o[1] = make_float4(v[4] - lse, v[5] - lse, v[6] - lse, v[7] - lse);
}

extern "C" void kernel_launch(void* const* d_in, const int* in_sizes, int n_in,
                              void* d_out, int out_size, void* d_ws, size_t ws_size,
                              hipStream_t stream) {
  const float* x   = (const float*)d_in[0];
  const float* adj = (const float*)d_in[1];
  const float* W1  = (const float*)d_in[2];
  const float* b1  = (const float*)d_in[3];
  const float* W2  = (const float*)d_in[4];
  const float* b2  = (const float*)d_in[5];
  const float* W3  = (const float*)d_in[6];
  const float* b3  = (const float*)d_in[7];
  float* out = (float*)d_out;

  char* ws = (char*)d_ws;
  size_t off = 0;
  ushort* W1T = (ushort*)(ws + off); off += (size_t)NH1 * NFEATC * 2;    // 256 KB
  ushort* W2T = (ushort*)(ws + off); off += (size_t)NH2 * NH1 * 2;      // 64 KB
  ushort* s1T = (ushort*)(ws + off); off += (size_t)NH1 * NROW * 2;     // 8 MiB
  ushort* h1  = (ushort*)(ws + off); off += (size_t)NROW * NH1 * 2;     // 8 MiB
  ushort* s2T = (ushort*)(ws + off); off += (size_t)NH2 * NROW * 2;     // 4 MiB
  ushort* h2  = (ushort*)(ws + off); off += (size_t)NROW * NH2 * 2;     // 4 MiB
  ushort* s3T = (ushort*)(ws + off); off += (size_t)16 * NROW * 2;      // 512 KB
  float*  part = (float*)(ws + off); off += (size_t)4 * NROW * NH2 * 4; // 32 MiB
  ushort* adjBF = (ushort*)(ws + off); off += (size_t)NROW * NROW * 2;  // 512 MiB

  transpose_conv<<<(NFEATC * NH1 + 255) / 256, 256, 0, stream>>>(W1, W1T, NFEATC, NH1);
  transpose_conv<<<(NH1 * NH2 + 255) / 256, 256, 0, stream>>>(W2, W2T, NH1, NH2);

  // s1T[256][16384] = (x @ W1)^T : 512 blocks
  gemm_pipe<64, 128, 32, 64, 1, true, 1, 2><<<512, 256, 0, stream>>>(
      x, W1T, s1T, nullptr, 256, 2, NROW, NH1, NFEATC);
  // h1 = relu(adj @ s1 + b1) + adjBF writeout : barrier-free direct, 1024 blocks
  h1_direct<<<1024, 256, 0, stream>>>(adj, s1T, b1, h1, adjBF);
  // s2T[128][16384] = (h1 @ W2)^T : 256 blocks
  gemm_pipe<64, 128, 32, 64, 1, false, 1, 2><<<256, 256, 0, stream>>>(
      h1, W2T, s2T, nullptr, 256, 1, NROW, NH2, NH1);
  // part[4][16384][128] = adjBF @ s2 : barrier-free direct, 1024 blocks
  h2_direct<<<1024, 256, 0, stream>>>(adjBF, s2T, part);
  // h2 = relu(sum part + b2)
  reduce_relu<<<NROW * NH2 / 4 / 256, 256, 0, stream>>>(
      part, b2, h2, NROW * NH2, NH2, 4);
  // s3T[16][16384] = (h2 @ W3)^T (bf16, zero-padded to 16 rows)
  mm_small<<<NROW / 64, 64, 0, stream>>>(h2, W3, s3T);
  // part[8][16384][16] = adjBF @ s3 (no-barrier streaming)
  gemm_fin<<<1024, 256, 0, stream>>>(adjBF, s3T, part);
  // out = log_softmax(sum part + b3)
  final_reduce<<<NROW / 256, 256, 0, stream>>>(part, b3, out);
}

// Round 9
// 1083.340 us; speedup vs baseline: 2.2208x; 2.2208x over previous
//
#include <hip/hip_runtime.h>
#include <hip/hip_bf16.h>

#define NROW 16384
#define NFEATC 512
#define NH1 256
#define NH2 128
#define NCLS 8

typedef __attribute__((ext_vector_type(8))) short short8;
typedef __attribute__((ext_vector_type(4))) float f32x4;

__device__ __forceinline__ ushort f2bf(float f) {
  union { float f; unsigned u; } v; v.f = f;
  unsigned r = v.u + 0x7FFFu + ((v.u >> 16) & 1u);
  return (ushort)(r >> 16);
}
__device__ __forceinline__ float bf2f(ushort h) {
  union { unsigned u; float f; } v; v.u = ((unsigned)h) << 16; return v.f;
}

// in [K][N] fp32 -> out [N][K] bf16
__global__ __launch_bounds__(256) void transpose_conv(
    const float* __restrict__ in, ushort* __restrict__ out, int K, int N) {
  int idx = blockIdx.x * 256 + threadIdx.x;
  if (idx < K * N) {
    int k = idx / N, n = idx % N;
    out[(size_t)n * K + k] = f2bf(in[idx]);
  }
}

// ---------------------------------------------------------------------------
// gemm_pipe: LDS-tiled GEMM, depth-1 reg prefetch + LDS double buffer, 4 waves.
// AMODE 0: A bf16 [M][K].
// AMODE 1: A fp32 [M][K] (on-the-fly cvt; optional adjBF writeout, n_blk==0).
// AMODE 2: A = relu(sum_{j<4} partA[j][M][K] + biasA[k])  (fused h1 reduce).
// OUTM 1: Out bf16 [N][M] (transposed store).
// OUTM 2: Out fp32 partial [ksl][M][N].
template<int BM, int BN, int WM, int WN, int BK, int KSPLIT, int AMODE, int OUTM, int MINW>
__global__ __launch_bounds__(256, MINW) void gemm_pipe(
    const void* __restrict__ Ap, const ushort* __restrict__ BT,
    void* __restrict__ Outp, ushort* __restrict__ adjBF,
    const float* __restrict__ bias, const float* __restrict__ biasA,
    const int nm, const int nn, const int M, const int N, const int K)
{
  constexpr int LDSK = BK + 8;
  constexpr int MR = WM / 16, NR = WN / 16;
  constexpr int nWc = BN / WN;
  static_assert((BM / WM) * (BN / WN) == 4, "4 waves");
  constexpr int AELEM = BM * BK / 256, ATPR = BK / AELEM;
  constexpr int BELEM = BN * BK / 256, BTPR = BK / BELEM;
  constexpr int A4s = (AMODE != 0) ? AELEM / 4 : 1;   // float4 count per stream
  constexpr int A8s = (AMODE == 0) ? AELEM / 8 : 1;   // short8 count
  constexpr int B8s = BELEM / 8;

  __shared__ ushort As[2][BM * LDSK];
  __shared__ ushort Bs[2][BN * LDSK];

  const int t = threadIdx.x, l = t & 63, wid = t >> 6;
  const int wr0 = (wid / nWc) * WM, wc0 = (wid % nWc) * WN;

  const int cpx = gridDim.x >> 3;
  const int flat = (blockIdx.x & 7) * cpx + (blockIdx.x >> 3);
  const int n_blk = flat % nn;
  const int m_blk = (flat / nn) % nm;
  const int ksl = flat / (nn * nm);
  const int bm0 = m_blk * BM, bn0 = n_blk * BN;
  const int kper = K / KSPLIT, kbase = ksl * kper;
  const int NT = kper / BK;

  const int ar = t / ATPR, ak = (t % ATPR) * AELEM;
  const int br = t / BTPR, bk = (t % BTPR) * BELEM;

  const float*  Af = (const float*)Ap + (size_t)(bm0 + ar) * K + kbase + ak;
  const ushort* Ab = (const ushort*)Ap + (size_t)(bm0 + ar) * K + kbase + ak;
  const ushort* Bp = BT + (size_t)(bn0 + br) * K + kbase + bk;
  ushort* adjW = (AMODE == 1 && adjBF) ? (adjBF + (size_t)(bm0 + ar) * K + kbase + ak) : nullptr;
  const bool wbf = (AMODE == 1) && (adjW != nullptr) && (n_blk == 0);
  const size_t MK = (size_t)M * K;

  f32x4 acc[MR][NR] = {};

  float4 aF[A4s];          // AMODE1: raw fp32; AMODE2: reduced+relu'd
  short8 aB[A8s];
  short8 bV[B8s];

  auto loadRegs = [&](int it) {
    const int ko = it * BK;
    if constexpr (AMODE == 1) {
      #pragma unroll
      for (int c = 0; c < A4s; c++) aF[c] = *(const float4*)(Af + ko + 4 * c);
    } else if constexpr (AMODE == 2) {
      #pragma unroll
      for (int c = 0; c < A4s; c++) {
        float4 s = *(const float4*)(Af + ko + 4 * c);
        #pragma unroll
        for (int j = 1; j < 4; j++) {
          float4 p = *(const float4*)(Af + j * MK + ko + 4 * c);
          s.x += p.x; s.y += p.y; s.z += p.z; s.w += p.w;
        }
        float4 b = *(const float4*)(biasA + kbase + ak + ko % BK + 4 * c);  // k-index bias
        // note: ko%BK==0 always (ko = it*BK), bias index = kbase+ak+4c valid only if K<=kper
        s.x = fmaxf(s.x + b.x, 0.0f); s.y = fmaxf(s.y + b.y, 0.0f);
        s.z = fmaxf(s.z + b.z, 0.0f); s.w = fmaxf(s.w + b.w, 0.0f);
        aF[c] = s;
      }
    } else {
      #pragma unroll
      for (int c = 0; c < A8s; c++) aB[c] = *(const short8*)(Ab + ko + 8 * c);
    }
    #pragma unroll
    for (int c = 0; c < B8s; c++) bV[c] = *(const short8*)(Bp + ko + 8 * c);
  };

  auto writeLds = [&](int buf, int it) {
    const int ko = it * BK;
    if constexpr (AMODE != 0) {
      #pragma unroll
      for (int c = 0; c < A4s; c++) {
        ushort4 v;
        v.x = f2bf(aF[c].x); v.y = f2bf(aF[c].y);
        v.z = f2bf(aF[c].z); v.w = f2bf(aF[c].w);
        *(ushort4*)&As[buf][ar * LDSK + ak + 4 * c] = v;
        if constexpr (AMODE == 1) {
          if (wbf) *(ushort4*)(adjW + ko + 4 * c) = v;
        }
      }
    } else {
      #pragma unroll
      for (int c = 0; c < A8s; c++)
        *(short8*)&As[buf][ar * LDSK + ak + 8 * c] = aB[c];
    }
    #pragma unroll
    for (int c = 0; c < B8s; c++)
      *(short8*)&Bs[buf][br * LDSK + bk + 8 * c] = bV[c];
  };

  auto compute = [&](int buf) {
    const int rr = l & 15;
    #pragma unroll
    for (int kk = 0; kk < BK / 32; kk++) {
      const int kb = kk * 32 + (l >> 4) * 8;
      short8 af[MR], bfv[NR];
      #pragma unroll
      for (int m = 0; m < MR; m++)
        af[m] = *(short8*)&As[buf][(wr0 + m * 16 + rr) * LDSK + kb];
      #pragma unroll
      for (int n = 0; n < NR; n++)
        bfv[n] = *(short8*)&Bs[buf][(wc0 + n * 16 + rr) * LDSK + kb];
      #pragma unroll
      for (int m = 0; m < MR; m++)
        #pragma unroll
        for (int n = 0; n < NR; n++)
          acc[m][n] = __builtin_amdgcn_mfma_f32_16x16x32_bf16(af[m], bfv[n], acc[m][n], 0, 0, 0);
    }
  };

  loadRegs(0);
  writeLds(0, 0);
  __syncthreads();
  for (int it = 0; it < NT; it++) {
    const int cur = it & 1;
    if (it + 1 < NT) loadRegs(it + 1);
    compute(cur);
    if (it + 1 < NT) writeLds(cur ^ 1, it + 1);
    __syncthreads();
  }

  #pragma unroll
  for (int m = 0; m < MR; m++) {
    const int row = bm0 + wr0 + m * 16 + (l >> 4) * 4;
    #pragma unroll
    for (int n = 0; n < NR; n++) {
      const int col = bn0 + wc0 + n * 16 + (l & 15);
      if constexpr (OUTM == 1) {
        ushort4 v;
        v.x = f2bf(acc[m][n][0]); v.y = f2bf(acc[m][n][1]);
        v.z = f2bf(acc[m][n][2]); v.w = f2bf(acc[m][n][3]);
        *(ushort4*)((ushort*)Outp + (size_t)col * M + row) = v;
      } else {
        float* o = (float*)Outp + (size_t)ksl * M * N;
        #pragma unroll
        for (int r = 0; r < 4; r++)
          o[(size_t)(row + r) * N + col] = acc[m][n][r];
      }
    }
  }
}

// ---------------------------------------------------------------------------
// relu_mm3: s3T[16][NROW] = (relu(sum_k part[k][m][:]+b2) @ W3)^T, zero-padded.
// Fuses the h2 reduce and the tiny W3 GEMM; h2 never materialized.
__global__ __launch_bounds__(256) void relu_mm3(
    const float* __restrict__ part, const float* __restrict__ b2,
    const float* __restrict__ W3, ushort* __restrict__ s3T) {
  __shared__ float w[NH2 * NCLS];
  __shared__ float bs[NH2];
  for (int i = threadIdx.x; i < NH2 * NCLS; i += 256) w[i] = W3[i];
  for (int i = threadIdx.x; i < NH2; i += 256) bs[i] = b2[i];
  __syncthreads();
  const int m = blockIdx.x * 256 + threadIdx.x;
  const float* p0 = part + (size_t)m * NH2;
  const size_t MK = (size_t)NROW * NH2;
  float acc[8] = {};
  #pragma unroll 4
  for (int c4 = 0; c4 < NH2; c4 += 4) {
    float4 s = *(const float4*)(p0 + c4);
    #pragma unroll
    for (int j = 1; j < 4; j++) {
      float4 p = *(const float4*)(p0 + j * MK + c4);
      s.x += p.x; s.y += p.y; s.z += p.z; s.w += p.w;
    }
    float h[4];
    h[0] = fmaxf(s.x + bs[c4 + 0], 0.0f);
    h[1] = fmaxf(s.y + bs[c4 + 1], 0.0f);
    h[2] = fmaxf(s.z + bs[c4 + 2], 0.0f);
    h[3] = fmaxf(s.w + bs[c4 + 3], 0.0f);
    #pragma unroll
    for (int j = 0; j < 4; j++)
      #pragma unroll
      for (int n = 0; n < 8; n++)
        acc[n] += h[j] * w[(c4 + j) * 8 + n];
  }
  #pragma unroll
  for (int n = 0; n < 8; n++) s3T[(size_t)n * NROW + m] = f2bf(acc[n]);
  #pragma unroll
  for (int n = 8; n < 16; n++) s3T[(size_t)n * NROW + m] = 0;
}

// ---------------------------------------------------------------------------
// gemm_fin: part[8][16384][16] = adjBF @ s3 (s3T padded to 16 cols).
// Pure register streaming; B is L3-resident. (Proven R7/R8.)
__global__ __launch_bounds__(256, 4) void gemm_fin(
    const ushort* __restrict__ adjBF, const ushort* __restrict__ s3T,
    float* __restrict__ part)
{
  const int t = threadIdx.x, l = t & 63, wid = t >> 6;   // 4 waves
  const int rr = l & 15, hi = l >> 4;

  const int cpx = gridDim.x >> 3;
  const int flat = (blockIdx.x & 7) * cpx + (blockIdx.x >> 3);
  const int m_blk = flat & 127;
  const int ksl = flat >> 7;                   // 0..7
  const int bm0 = m_blk * 128;
  const int kbase = ksl * 2048;

  const ushort* A0 = adjBF + (size_t)(bm0 + wid * 32 + rr) * NROW + kbase + hi * 8;
  const ushort* A1 = A0 + (size_t)16 * NROW;
  const ushort* Bp = s3T + (size_t)rr * NROW + kbase + hi * 8;

  f32x4 acc0 = {}, acc1 = {};
  #pragma unroll 8
  for (int k = 0; k < 64; k++) {
    short8 a0 = *(const short8*)(A0 + k * 32);
    short8 a1 = *(const short8*)(A1 + k * 32);
    short8 b  = *(const short8*)(Bp + k * 32);
    acc0 = __builtin_amdgcn_mfma_f32_16x16x32_bf16(a0, b, acc0, 0, 0, 0);
    acc1 = __builtin_amdgcn_mfma_f32_16x16x32_bf16(a1, b, acc1, 0, 0, 0);
  }

  float* o = part + (size_t)ksl * NROW * 16;
  #pragma unroll
  for (int r = 0; r < 4; r++) {
    o[(size_t)(bm0 + wid * 32 + hi * 4 + r) * 16 + rr] = acc0[r];
    o[(size_t)(bm0 + wid * 32 + 16 + hi * 4 + r) * 16 + rr] = acc1[r];
  }
}

// out[NROW][8] = log_softmax(sum_ksl part + b3), KS=8
__global__ __launch_bounds__(256) void final_reduce(
    const float* __restrict__ part, const float* __restrict__ b3,
    float* __restrict__ out) {
  const int m = blockIdx.x * 256 + threadIdx.x;
  float4 s0 = make_float4(0, 0, 0, 0), s1 = make_float4(0, 0, 0, 0);
  #pragma unroll
  for (int k = 0; k < 8; k++) {
    const float4* p = (const float4*)(part + ((size_t)k * NROW + m) * 16);
    float4 a = p[0], b = p[1];
    s0.x += a.x; s0.y += a.y; s0.z += a.z; s0.w += a.w;
    s1.x += b.x; s1.y += b.y; s1.z += b.z; s1.w += b.w;
  }
  float v[8];
  v[0] = s0.x + b3[0]; v[1] = s0.y + b3[1]; v[2] = s0.z + b3[2]; v[3] = s0.w + b3[3];
  v[4] = s1.x + b3[4]; v[5] = s1.y + b3[5]; v[6] = s1.z + b3[6]; v[7] = s1.w + b3[7];
  float mx = v[0];
  #pragma unroll
  for (int n = 1; n < 8; n++) mx = fmaxf(mx, v[n]);
  float s = 0.0f;
  #pragma unroll
  for (int n = 0; n < 8; n++) s += expf(v[n] - mx);
  const float lse = logf(s) + mx;
  float4* o = (float4*)(out + (size_t)m * 8);
  o[0] = make_float4(v[0] - lse, v[1] - lse, v[2] - lse, v[3] - lse);
  o[1] = make_float4(v[4] - lse, v[5] - lse, v[6] - lse, v[7] - lse);
}

extern "C" void kernel_launch(void* const* d_in, const int* in_sizes, int n_in,
                              void* d_out, int out_size, void* d_ws, size_t ws_size,
                              hipStream_t stream) {
  const float* x   = (const float*)d_in[0];
  const float* adj = (const float*)d_in[1];
  const float* W1  = (const float*)d_in[2];
  const float* b1  = (const float*)d_in[3];
  const float* W2  = (const float*)d_in[4];
  const float* b2  = (const float*)d_in[5];
  const float* W3  = (const float*)d_in[6];
  const float* b3  = (const float*)d_in[7];
  float* out = (float*)d_out;

  char* ws = (char*)d_ws;
  size_t off = 0;
  ushort* W1T = (ushort*)(ws + off); off += (size_t)NH1 * NFEATC * 2;    // 256 KB
  ushort* W2T = (ushort*)(ws + off); off += (size_t)NH2 * NH1 * 2;      // 64 KB
  ushort* s1T = (ushort*)(ws + off); off += (size_t)NH1 * NROW * 2;     // 8 MiB
  ushort* s2T = (ushort*)(ws + off); off += (size_t)NH2 * NROW * 2;     // 4 MiB
  ushort* s3T = (ushort*)(ws + off); off += (size_t)16 * NROW * 2;      // 512 KB
  float*  part = (float*)(ws + off); off += (size_t)4 * NROW * NH1 * 4; // 64 MiB
  ushort* adjBF = (ushort*)(ws + off); off += (size_t)NROW * NROW * 2;  // 512 MiB

  transpose_conv<<<(NFEATC * NH1 + 255) / 256, 256, 0, stream>>>(W1, W1T, NFEATC, NH1);
  transpose_conv<<<(NH1 * NH2 + 255) / 256, 256, 0, stream>>>(W2, W2T, NH1, NH2);

  // s1T[256][16384] = (x @ W1)^T : BK=64, 512 blocks
  gemm_pipe<64, 128, 32, 64, 64, 1, 1, 1, 2><<<512, 256, 0, stream>>>(
      x, W1T, s1T, nullptr, nullptr, nullptr, 256, 2, NROW, NH1, NFEATC);
  // part[4][16384][256] = adj @ s1 (split-K=4, BK=32, 3 blocks/CU) + adjBF
  gemm_pipe<128, 128, 64, 64, 32, 4, 1, 2, 3><<<1024, 256, 0, stream>>>(
      adj, s1T, part, adjBF, nullptr, nullptr, 128, 2, NROW, NH1, NROW);
  // s2T[128][16384] = (relu(sum part + b1) @ W2)^T  : fused h1 reduce, 256 blocks
  gemm_pipe<64, 128, 32, 64, 64, 1, 2, 1, 2><<<256, 256, 0, stream>>>(
      part, W2T, s2T, nullptr, nullptr, b1, 256, 1, NROW, NH2, NH1);
  // part[4][16384][128] = adjBF @ s2 (split-K=4, BK=32, 3 blocks/CU)
  gemm_pipe<128, 128, 64, 64, 32, 4, 0, 2, 3><<<1024, 256, 0, stream>>>(
      adjBF, s2T, part, nullptr, nullptr, nullptr, 128, 1, NROW, NH2, NROW);
  // s3T[16][16384] = (relu(sum part + b2) @ W3)^T : fused, 64 blocks
  relu_mm3<<<NROW / 256, 256, 0, stream>>>(part, b2, W3, s3T);
  // part[8][16384][16] = adjBF @ s3 (no-barrier streaming)
  gemm_fin<<<1024, 256, 0, stream>>>(adjBF, s3T, part);
  // out = log_softmax(sum part + b3)
  final_reduce<<<NROW / 256, 256, 0, stream>>>(part, b3, out);
}